// Round 1
// baseline (684.946 us; speedup 1.0000x reference)
//
#include <hip/hip_runtime.h>

// MaxPool3d k=2 s=2, input (2,32,128,128,128) f32 -> output (2,32,64,64,64) f32.
// Memory-bound: 512 MiB in + 64 MiB out, zero reuse. Roofline ~96 us @ 6.3 TB/s.
//
// Mapping: each thread produces TWO adjacent output-w elements (one float2).
// It loads 4x float4 (w-run of 4 inputs at (d,h),(d,h+1),(d+1,h),(d+1,h+1)),
// i.e. the complete 2x2x4 input footprint of those two windows.
// Consecutive lanes -> consecutive 16B input segments (fully coalesced),
// consecutive 8B output segments.

static constexpr int W_IN  = 128;
static constexpr int H_IN  = 128;
static constexpr int D_IN  = 128;
static constexpr int BC    = 2 * 32;            // fused batch*channel
static constexpr int W_OUT = 64, H_OUT = 64, D_OUT = 64;
// threads total = BC * D_OUT * H_OUT * (W_OUT/2) = 64*64*64*32 = 8,388,608

__global__ __launch_bounds__(256)
void maxpool3d_k2s2_kernel(const float* __restrict__ in, float* __restrict__ out) {
    const int tid = blockIdx.x * blockDim.x + threadIdx.x;

    const int owp = tid & 31;          // output-w pair index: ow = 2*owp, 2*owp+1
    const int oh  = (tid >> 5)  & 63;
    const int od  = (tid >> 11) & 63;
    const int bc  = tid >> 17;         // 0..63

    // input base: (bc, 2*od, 2*oh, 4*owp). All fits in int (max ~134M).
    const int in_base = (((bc * D_IN) + (od << 1)) * H_IN + (oh << 1)) * W_IN + (owp << 2);

    const float4 a = *(const float4*)(in + in_base);                     // (d, h)
    const float4 b = *(const float4*)(in + in_base + W_IN);              // (d, h+1)
    const float4 c = *(const float4*)(in + in_base + H_IN * W_IN);       // (d+1, h)
    const float4 d = *(const float4*)(in + in_base + H_IN * W_IN + W_IN);// (d+1, h+1)

    const float m0 = fmaxf(fmaxf(fmaxf(a.x, a.y), fmaxf(b.x, b.y)),
                           fmaxf(fmaxf(c.x, c.y), fmaxf(d.x, d.y)));
    const float m1 = fmaxf(fmaxf(fmaxf(a.z, a.w), fmaxf(b.z, b.w)),
                           fmaxf(fmaxf(c.z, c.w), fmaxf(d.z, d.w)));

    const int out_base = (((bc * D_OUT) + od) * H_OUT + oh) * W_OUT + (owp << 1);
    *(float2*)(out + out_base) = make_float2(m0, m1);
}

extern "C" void kernel_launch(void* const* d_in, const int* in_sizes, int n_in,
                              void* d_out, int out_size, void* d_ws, size_t ws_size,
                              hipStream_t stream) {
    const float* x = (const float*)d_in[0];
    float* y = (float*)d_out;
    const int total_threads = BC * D_OUT * H_OUT * (W_OUT / 2); // 8,388,608
    const int block = 256;
    const int grid = total_threads / block;                      // 32,768
    maxpool3d_k2s2_kernel<<<grid, block, 0, stream>>>(x, y);
}

// Round 2
// 667.495 us; speedup vs baseline: 1.0261x; 1.0261x over previous
//
#include <hip/hip_runtime.h>

// MaxPool3d k=2 s=2, input (2,32,128,128,128) f32 -> output (2,32,64,64,64) f32.
// Streaming, zero-reuse: 512 MiB read once + 64 MiB written once.
// Roofline ~96 us @ 6.3 TB/s achievable.
//
// v2: each thread produces a 2x2 (h,w) patch of outputs for one (bc, od):
//   - 8 dense float4 nontemporal loads (rows ih..ih+3 in slices id, id+1)
//   - 2 float2 nontemporal stores (output rows oh, oh+1)
// Lanes 0..31 of a wave cover one contiguous 512B row segment per load
// instruction -> fully coalesced. 8 outstanding loads/thread for MLP.
// Nontemporal: input/output have zero reuse; keep them out of L2 LRU.

using f32x4 = __attribute__((ext_vector_type(4))) float;
using f32x2 = __attribute__((ext_vector_type(2))) float;

static constexpr int W_IN = 128, H_IN = 128, D_IN = 128;
static constexpr int BC = 64;                     // 2*32 fused
static constexpr int W_OUT = 64, H_OUT = 64, D_OUT = 64;
// threads = BC * D_OUT * (H_OUT/2) * (W_OUT/2) = 64*64*32*32 = 4,194,304

__global__ __launch_bounds__(256)
void maxpool3d_k2s2_v2(const float* __restrict__ in, float* __restrict__ out) {
    const int tid = blockIdx.x * blockDim.x + threadIdx.x;

    const int owp = tid & 31;          // output w pair: ow = 2*owp, 2*owp+1
    const int ohp = (tid >> 5) & 31;   // output h pair: oh = 2*ohp, 2*ohp+1
    const int od  = (tid >> 10) & 63;
    const int bc  = tid >> 16;         // 0..63

    const int iw = owp << 2;           // 4 input floats in w
    const int ih = ohp << 2;           // 4 input rows in h
    const int base = ((bc * D_IN + (od << 1)) * H_IN + ih) * W_IN + iw;
    const int slice = H_IN * W_IN;     // 16384

    // slice id = 2*od : rows ih+0..3 ; slice id+1 : rows ih+0..3
    const f32x4 r0 = __builtin_nontemporal_load((const f32x4*)(in + base));
    const f32x4 r1 = __builtin_nontemporal_load((const f32x4*)(in + base + W_IN));
    const f32x4 r2 = __builtin_nontemporal_load((const f32x4*)(in + base + 2 * W_IN));
    const f32x4 r3 = __builtin_nontemporal_load((const f32x4*)(in + base + 3 * W_IN));
    const f32x4 s0 = __builtin_nontemporal_load((const f32x4*)(in + base + slice));
    const f32x4 s1 = __builtin_nontemporal_load((const f32x4*)(in + base + slice + W_IN));
    const f32x4 s2 = __builtin_nontemporal_load((const f32x4*)(in + base + slice + 2 * W_IN));
    const f32x4 s3 = __builtin_nontemporal_load((const f32x4*)(in + base + slice + 3 * W_IN));

    // output (oh, ow0/ow1): input rows ih, ih+1 of both slices
    const float m00 = fmaxf(fmaxf(fmaxf(r0.x, r0.y), fmaxf(r1.x, r1.y)),
                            fmaxf(fmaxf(s0.x, s0.y), fmaxf(s1.x, s1.y)));
    const float m01 = fmaxf(fmaxf(fmaxf(r0.z, r0.w), fmaxf(r1.z, r1.w)),
                            fmaxf(fmaxf(s0.z, s0.w), fmaxf(s1.z, s1.w)));
    // output (oh+1, ow0/ow1): input rows ih+2, ih+3 of both slices
    const float m10 = fmaxf(fmaxf(fmaxf(r2.x, r2.y), fmaxf(r3.x, r3.y)),
                            fmaxf(fmaxf(s2.x, s2.y), fmaxf(s3.x, s3.y)));
    const float m11 = fmaxf(fmaxf(fmaxf(r2.z, r2.w), fmaxf(r3.z, r3.w)),
                            fmaxf(fmaxf(s2.z, s2.w), fmaxf(s3.z, s3.w)));

    const int oh = ohp << 1;
    const int ow = owp << 1;
    const int out_base = ((bc * D_OUT + od) * H_OUT + oh) * W_OUT + ow;
    __builtin_nontemporal_store((f32x2){m00, m01}, (f32x2*)(out + out_base));
    __builtin_nontemporal_store((f32x2){m10, m11}, (f32x2*)(out + out_base + W_OUT));
}

extern "C" void kernel_launch(void* const* d_in, const int* in_sizes, int n_in,
                              void* d_out, int out_size, void* d_ws, size_t ws_size,
                              hipStream_t stream) {
    const float* x = (const float*)d_in[0];
    float* y = (float*)d_out;
    const int total_threads = BC * D_OUT * (H_OUT / 2) * (W_OUT / 2); // 4,194,304
    const int block = 256;
    const int grid = total_threads / block;                            // 16,384
    maxpool3d_k2s2_v2<<<grid, block, 0, stream>>>(x, y);
}